// Round 1
// baseline (2171.969 us; speedup 1.0000x reference)
//
#include <hip/hip_runtime.h>
#include <math.h>

// ============================================================================
// ViT block: patch-embed -> LN+PE -> FFN -> windowed attn -> +res -> FFN -> +res
// B=32, C=3, H=W=512, P=16 -> M = 32*1024 = 32768 tokens, D=256, HF=1024
// Round 1: fp32 correctness-first baseline. GEMMs: 128x128x16 tiles, 8x8/thread.
// ============================================================================

#define M_TOK 32768

__device__ __forceinline__ float gelu_tanh(float x) {
    // jax.nn.gelu(approximate=True)
    const float c0 = 0.7978845608028654f; // sqrt(2/pi)
    float inner = c0 * (x + 0.044715f * x * x * x);
    return 0.5f * x * (1.0f + tanhf(inner));
}

// ---------------------------------------------------------------------------
// Patch-embed GEMM: out[m][d] = sum_p patch[m][p] * w[d][p] + bias[d]
// m = b*1024 + hh*32 + ww ; p = c*256 + ph*16 + pw ; x: [32][3][512][512]
// Tile 128x128, BK=16 (one BK slice of a patch row = 16 contiguous pixels).
// ---------------------------------------------------------------------------
__global__ __launch_bounds__(256) void patch_embed_kernel(
    const float* __restrict__ x, const float* __restrict__ w,
    const float* __restrict__ bias, float* __restrict__ out)
{
    __shared__ float As[128][17];
    __shared__ float Bs[128][17];
    const int t  = threadIdx.x;
    const int m0 = blockIdx.x * 128;
    const int n0 = blockIdx.y * 128;

    const int lr = t >> 1;          // 0..127 (tile row loaded by this thread)
    const int lc = (t & 1) * 8;     // 0 or 8 (k-offset within BK)

    const int m  = m0 + lr;
    const int b  = m >> 10;
    const int n  = m & 1023;
    const int hh = n >> 5, ww = n & 31;
    const float* xbase = x + (((size_t)(b * 3)) * 512 + (size_t)(hh * 16)) * 512 + ww * 16;
    const float* wrow  = w + (size_t)(n0 + lr) * 768;

    float acc[8][8];
#pragma unroll
    for (int i = 0; i < 8; i++)
#pragma unroll
        for (int j = 0; j < 8; j++) acc[i][j] = 0.0f;

    const int tr = t >> 4, tc = t & 15;

    for (int k0 = 0; k0 < 768; k0 += 16) {
        const int p  = k0 + lc;
        const int c  = p >> 8;
        const int ph = (p >> 4) & 15;
        const int pw = p & 15;
        const float* src = xbase + ((size_t)c * 512 + ph) * 512 + pw;
        float4 a0 = *(const float4*)(src);
        float4 a1 = *(const float4*)(src + 4);
        float4 b0 = *(const float4*)(wrow + k0 + lc);
        float4 b1 = *(const float4*)(wrow + k0 + lc + 4);
        __syncthreads();
        As[lr][lc+0]=a0.x; As[lr][lc+1]=a0.y; As[lr][lc+2]=a0.z; As[lr][lc+3]=a0.w;
        As[lr][lc+4]=a1.x; As[lr][lc+5]=a1.y; As[lr][lc+6]=a1.z; As[lr][lc+7]=a1.w;
        Bs[lr][lc+0]=b0.x; Bs[lr][lc+1]=b0.y; Bs[lr][lc+2]=b0.z; Bs[lr][lc+3]=b0.w;
        Bs[lr][lc+4]=b1.x; Bs[lr][lc+5]=b1.y; Bs[lr][lc+6]=b1.z; Bs[lr][lc+7]=b1.w;
        __syncthreads();
#pragma unroll
        for (int kk = 0; kk < 16; kk++) {
            float a[8], bb[8];
#pragma unroll
            for (int i = 0; i < 8; i++) a[i] = As[tr*8+i][kk];
#pragma unroll
            for (int j = 0; j < 8; j++) bb[j] = Bs[tc*8+j][kk];
#pragma unroll
            for (int i = 0; i < 8; i++)
#pragma unroll
                for (int j = 0; j < 8; j++) acc[i][j] = fmaf(a[i], bb[j], acc[i][j]);
        }
    }

#pragma unroll
    for (int i = 0; i < 8; i++) {
        const int row = m0 + tr * 8 + i;
        float* dst = out + (size_t)row * 256 + n0 + tc * 8;
        float4 o0, o1;
        o0.x = acc[i][0] + bias[n0 + tc*8 + 0];
        o0.y = acc[i][1] + bias[n0 + tc*8 + 1];
        o0.z = acc[i][2] + bias[n0 + tc*8 + 2];
        o0.w = acc[i][3] + bias[n0 + tc*8 + 3];
        o1.x = acc[i][4] + bias[n0 + tc*8 + 4];
        o1.y = acc[i][5] + bias[n0 + tc*8 + 5];
        o1.z = acc[i][6] + bias[n0 + tc*8 + 6];
        o1.w = acc[i][7] + bias[n0 + tc*8 + 7];
        *(float4*)dst = o0;
        *(float4*)(dst + 4) = o1;
    }
}

// ---------------------------------------------------------------------------
// Generic GEMM: out[m][n] = A[m][:] . W[n][:] + bias[n]  (+gelu) (+res[m][n])
// M, N multiples of 128; K multiple of 16.
// ---------------------------------------------------------------------------
template<bool GELU, bool RES>
__global__ __launch_bounds__(256) void gemm_bias_kernel(
    const float* __restrict__ A, const float* __restrict__ W,
    const float* __restrict__ bias, const float* __restrict__ res,
    float* __restrict__ out, int M, int N, int K)
{
    __shared__ float As[128][17];
    __shared__ float Bs[128][17];
    const int t  = threadIdx.x;
    const int m0 = blockIdx.x * 128;
    const int n0 = blockIdx.y * 128;

    const int lr = t >> 1;
    const int lc = (t & 1) * 8;

    const float* arow = A + (size_t)(m0 + lr) * K;
    const float* wrow = W + (size_t)(n0 + lr) * K;

    float acc[8][8];
#pragma unroll
    for (int i = 0; i < 8; i++)
#pragma unroll
        for (int j = 0; j < 8; j++) acc[i][j] = 0.0f;

    const int tr = t >> 4, tc = t & 15;

    for (int k0 = 0; k0 < K; k0 += 16) {
        float4 a0 = *(const float4*)(arow + k0 + lc);
        float4 a1 = *(const float4*)(arow + k0 + lc + 4);
        float4 b0 = *(const float4*)(wrow + k0 + lc);
        float4 b1 = *(const float4*)(wrow + k0 + lc + 4);
        __syncthreads();
        As[lr][lc+0]=a0.x; As[lr][lc+1]=a0.y; As[lr][lc+2]=a0.z; As[lr][lc+3]=a0.w;
        As[lr][lc+4]=a1.x; As[lr][lc+5]=a1.y; As[lr][lc+6]=a1.z; As[lr][lc+7]=a1.w;
        Bs[lr][lc+0]=b0.x; Bs[lr][lc+1]=b0.y; Bs[lr][lc+2]=b0.z; Bs[lr][lc+3]=b0.w;
        Bs[lr][lc+4]=b1.x; Bs[lr][lc+5]=b1.y; Bs[lr][lc+6]=b1.z; Bs[lr][lc+7]=b1.w;
        __syncthreads();
#pragma unroll
        for (int kk = 0; kk < 16; kk++) {
            float a[8], bb[8];
#pragma unroll
            for (int i = 0; i < 8; i++) a[i] = As[tr*8+i][kk];
#pragma unroll
            for (int j = 0; j < 8; j++) bb[j] = Bs[tc*8+j][kk];
#pragma unroll
            for (int i = 0; i < 8; i++)
#pragma unroll
                for (int j = 0; j < 8; j++) acc[i][j] = fmaf(a[i], bb[j], acc[i][j]);
        }
    }

#pragma unroll
    for (int i = 0; i < 8; i++) {
        const int row = m0 + tr * 8 + i;
        float* dst = out + (size_t)row * N + n0 + tc * 8;
        const float* rsrc = RES ? (res + (size_t)row * N + n0 + tc * 8) : nullptr;
        float v[8];
#pragma unroll
        for (int j = 0; j < 8; j++) {
            v[j] = acc[i][j] + bias[n0 + tc*8 + j];
            if (GELU) v[j] = gelu_tanh(v[j]);
            if (RES)  v[j] += rsrc[j];
        }
        float4 o0, o1;
        o0.x=v[0]; o0.y=v[1]; o0.z=v[2]; o0.w=v[3];
        o1.x=v[4]; o1.y=v[5]; o1.z=v[6]; o1.w=v[7];
        *(float4*)dst = o0;
        *(float4*)(dst + 4) = o1;
    }
}

// ---------------------------------------------------------------------------
// LayerNorm + sinusoidal PE. One block = one token row (256 features).
// ---------------------------------------------------------------------------
__global__ __launch_bounds__(256) void ln_pe_kernel(
    const float* __restrict__ in, const float* __restrict__ w,
    const float* __restrict__ b, float* __restrict__ out)
{
    const int m = blockIdx.x;
    const int d = threadIdx.x;
    float v = in[(size_t)m * 256 + d];

    float s = v, s2 = v * v;
#pragma unroll
    for (int off = 32; off > 0; off >>= 1) {
        s  += __shfl_down(s,  off, 64);
        s2 += __shfl_down(s2, off, 64);
    }
    __shared__ float ss[4], ss2[4], stats[2];
    const int lane = d & 63, wid = d >> 6;
    if (lane == 0) { ss[wid] = s; ss2[wid] = s2; }
    __syncthreads();
    if (d == 0) {
        float a  = ss[0] + ss[1] + ss[2] + ss[3];
        float a2 = ss2[0] + ss2[1] + ss2[2] + ss2[3];
        float mean = a * (1.0f / 256.0f);
        float var  = a2 * (1.0f / 256.0f) - mean * mean;
        stats[0] = mean;
        stats[1] = rsqrtf(var + 1e-5f);
    }
    __syncthreads();
    const float mean = stats[0], rstd = stats[1];

    const int pos = m & 1023;
    const int ieven = d & ~1;
    float div = expf(-9.210340371976184f * (float)ieven * (1.0f / 256.0f));
    float ang = (float)pos * div;
    float pe = (d & 1) ? cosf(ang) : sinf(ang);

    out[(size_t)m * 256 + d] = (v - mean) * rstd * w[d] + b[d] + pe;
}

// ---------------------------------------------------------------------------
// Windowed attention. One block = one (batch, window, head): 64x32 q/k/v.
// qkv: [32768][768], feature e = s*256 + h*32 + i. out: [32768][256].
// ---------------------------------------------------------------------------
__global__ __launch_bounds__(256) void attn_kernel(
    const float* __restrict__ qkv, float* __restrict__ out)
{
    const int blk = blockIdx.x;        // 0..4095
    const int h = blk & 7;
    const int w = (blk >> 3) & 15;
    const int b = blk >> 7;
    const int m_base = b * 1024 + w * 64;

    __shared__ float Q[64][33], Kt[64][33], V[64][33];
    __shared__ float S[64][65];

    const int t = threadIdx.x;
    {   // loads: row = t>>2, 8 floats at c0=(t&3)*8 per matrix
        const int row = t >> 2;
        const int c0 = (t & 3) * 8;
        const float* base = qkv + (size_t)(m_base + row) * 768 + h * 32 + c0;
        float4 q0 = *(const float4*)(base);
        float4 q1 = *(const float4*)(base + 4);
        float4 k0 = *(const float4*)(base + 256);
        float4 k1 = *(const float4*)(base + 260);
        float4 v0 = *(const float4*)(base + 512);
        float4 v1 = *(const float4*)(base + 516);
        Q[row][c0+0]=q0.x; Q[row][c0+1]=q0.y; Q[row][c0+2]=q0.z; Q[row][c0+3]=q0.w;
        Q[row][c0+4]=q1.x; Q[row][c0+5]=q1.y; Q[row][c0+6]=q1.z; Q[row][c0+7]=q1.w;
        Kt[row][c0+0]=k0.x; Kt[row][c0+1]=k0.y; Kt[row][c0+2]=k0.z; Kt[row][c0+3]=k0.w;
        Kt[row][c0+4]=k1.x; Kt[row][c0+5]=k1.y; Kt[row][c0+6]=k1.z; Kt[row][c0+7]=k1.w;
        V[row][c0+0]=v0.x; V[row][c0+1]=v0.y; V[row][c0+2]=v0.z; V[row][c0+3]=v0.w;
        V[row][c0+4]=v1.x; V[row][c0+5]=v1.y; V[row][c0+6]=v1.z; V[row][c0+7]=v1.w;
    }
    __syncthreads();

    {   // scores: thread handles row qi = t>>2, 16 cols starting (t&3)*16
        const int qi = t >> 2;
        const int kb = (t & 3) * 16;
        const float scale = 0.17677669529663687f; // 1/sqrt(32)
        float qreg[32];
#pragma unroll
        for (int i = 0; i < 32; i++) qreg[i] = Q[qi][i];
        for (int kk = 0; kk < 16; kk++) {
            const int ki = kb + kk;
            float a = 0.0f;
#pragma unroll
            for (int i = 0; i < 32; i++) a = fmaf(qreg[i], Kt[ki][i], a);
            S[qi][ki] = a * scale;
        }
    }
    __syncthreads();

    if (t < 64) {   // softmax over row t
        float mx = -1e30f;
        for (int k = 0; k < 64; k++) mx = fmaxf(mx, S[t][k]);
        float sum = 0.0f;
        for (int k = 0; k < 64; k++) { float e = expf(S[t][k] - mx); S[t][k] = e; sum += e; }
        float inv = 1.0f / sum;
        for (int k = 0; k < 64; k++) S[t][k] *= inv;
    }
    __syncthreads();

    {   // out: thread handles row qi = t&63, 8 cols at i0=(t>>6)*8
        const int qi = t & 63;
        const int i0 = (t >> 6) * 8;
        float acc[8];
#pragma unroll
        for (int j = 0; j < 8; j++) acc[j] = 0.0f;
        for (int k = 0; k < 64; k++) {
            float s = S[qi][k];
#pragma unroll
            for (int j = 0; j < 8; j++) acc[j] = fmaf(s, V[k][i0 + j], acc[j]);
        }
        float* dst = out + (size_t)(m_base + qi) * 256 + h * 32 + i0;
        float4 o0, o1;
        o0.x=acc[0]; o0.y=acc[1]; o0.z=acc[2]; o0.w=acc[3];
        o1.x=acc[4]; o1.y=acc[5]; o1.z=acc[6]; o1.w=acc[7];
        *(float4*)dst = o0;
        *(float4*)(dst + 4) = o1;
    }
}

// ---------------------------------------------------------------------------
// Workspace layout (bytes):
//   A : 0         .. 33.5MB   h1 (LN+PE output, residual for attn)
//   B : 33.5MB    .. 167.8MB  gelu hidden (134MB) / qkv (100MB) reuse
//   C : 167.8MB   .. 201.3MB  h0 / ffn1-out / attn-out reuse
// Total 201,326,592 B.
// ---------------------------------------------------------------------------
extern "C" void kernel_launch(void* const* d_in, const int* in_sizes, int n_in,
                              void* d_out, int out_size, void* d_ws, size_t ws_size,
                              hipStream_t stream)
{
    const float* x      = (const float*)d_in[0];
    const float* conv_w = (const float*)d_in[1];
    const float* conv_b = (const float*)d_in[2];
    const float* ln_w   = (const float*)d_in[3];
    const float* ln_b   = (const float*)d_in[4];
    const float* qkv_w  = (const float*)d_in[5];
    const float* qkv_b  = (const float*)d_in[6];
    const float* proj_w = (const float*)d_in[7];
    const float* proj_b = (const float*)d_in[8];
    const float* ff_w1  = (const float*)d_in[9];
    const float* ff_b1  = (const float*)d_in[10];
    const float* ff_w2  = (const float*)d_in[11];
    const float* ff_b2  = (const float*)d_in[12];
    float* out = (float*)d_out;

    char* ws = (char*)d_ws;
    float* Abuf = (float*)(ws);
    float* Bbuf = (float*)(ws + 33554432);
    float* Cbuf = (float*)(ws + 33554432 + 134217728);

    const int M = M_TOK;
    dim3 blk(256);

    // K1: patch embed -> C (h0)
    patch_embed_kernel<<<dim3(M/128, 2), blk, 0, stream>>>(x, conv_w, conv_b, Cbuf);
    // K2: LN + PE -> A (h1, identity #1)
    ln_pe_kernel<<<dim3(M), blk, 0, stream>>>(Cbuf, ln_w, ln_b, Abuf);
    // K3: FFN1a: gelu(A @ w1^T + b1) -> B
    gemm_bias_kernel<true, false><<<dim3(M/128, 8), blk, 0, stream>>>(
        Abuf, ff_w1, ff_b1, nullptr, Bbuf, M, 1024, 256);
    // K4: FFN1b: B @ w2^T + b2 -> C
    gemm_bias_kernel<false, false><<<dim3(M/128, 2), blk, 0, stream>>>(
        Bbuf, ff_w2, ff_b2, nullptr, Cbuf, M, 256, 1024);
    // K5: qkv: C @ qkv_w^T + qkv_b -> B
    gemm_bias_kernel<false, false><<<dim3(M/128, 6), blk, 0, stream>>>(
        Cbuf, qkv_w, qkv_b, nullptr, Bbuf, M, 768, 256);
    // K6: windowed attention: B -> C
    attn_kernel<<<dim3(4096), blk, 0, stream>>>(Bbuf, Cbuf);
    // K7: proj + residual(h1): C @ proj_w^T + proj_b + A -> out (h2, identity #2)
    gemm_bias_kernel<false, true><<<dim3(M/128, 2), blk, 0, stream>>>(
        Cbuf, proj_w, proj_b, Abuf, out, M, 256, 256);
    // K8: FFN2a: gelu(out @ w1^T + b1) -> B
    gemm_bias_kernel<true, false><<<dim3(M/128, 8), blk, 0, stream>>>(
        out, ff_w1, ff_b1, nullptr, Bbuf, M, 1024, 256);
    // K9: FFN2b + final residual: B @ w2^T + b2 + out -> out
    gemm_bias_kernel<false, true><<<dim3(M/128, 2), blk, 0, stream>>>(
        Bbuf, ff_w2, ff_b2, out, out, M, 256, 1024);
}

// Round 2
// 559.824 us; speedup vs baseline: 3.8797x; 3.8797x over previous
//
#include <hip/hip_runtime.h>
#include <math.h>

// ============================================================================
// ViT block on MI355X — Round 2: bf16 MFMA GEMMs (m93-style 128x128 tile).
// B=32, C=3, H=W=512, P=16 -> M=32768 tokens, D=256, HF=1024.
// Dataflow: activations bf16 between GEMMs; residual path fp32.
// ============================================================================

#define M_TOK 32768

typedef __attribute__((ext_vector_type(8))) short  short8;   // 8 bf16 (4 VGPRs)
typedef __attribute__((ext_vector_type(4))) float  f32x4;
typedef __attribute__((ext_vector_type(8))) unsigned short us8v;
typedef __attribute__((ext_vector_type(4))) unsigned short us4v;

__device__ __forceinline__ unsigned short f2b(float f) {
    union { float f; unsigned u; } c; c.f = f;
    unsigned r = c.u + 0x7fffu + ((c.u >> 16) & 1u);   // RNE
    return (unsigned short)(r >> 16);
}
__device__ __forceinline__ float b2f(unsigned short u) {
    union { unsigned u; float f; } c; c.u = ((unsigned)u) << 16;
    return c.f;
}
__device__ __forceinline__ float gelu_tanh(float x) {
    const float c0 = 0.7978845608028654f; // sqrt(2/pi)
    float inner = c0 * (x + 0.044715f * x * x * x);
    return 0.5f * x * (1.0f + tanhf(inner));
}

// ---------------------------------------------------------------------------
// fp32 -> bf16 convert (n % 4 == 0)
// ---------------------------------------------------------------------------
__global__ __launch_bounds__(256) void cvt_f2b_kernel(
    const float* __restrict__ in, unsigned short* __restrict__ out, int n)
{
    int i = (blockIdx.x * 256 + threadIdx.x) * 4;
    if (i >= n) return;
    float4 v = *(const float4*)(in + i);
    us4v o;
    o[0] = f2b(v.x); o[1] = f2b(v.y); o[2] = f2b(v.z); o[3] = f2b(v.w);
    *(us4v*)(out + i) = o;
}

// ---------------------------------------------------------------------------
// MFMA GEMM: C[m][n] = sum_k A[m][k] * W[n][k]  (+bias, opt gelu/res/out-fmt)
// A: bf16 [M][K], W: bf16 [N][K]. 128x128 tile, BK=32, 256 thr = 4 waves 2x2.
// ---------------------------------------------------------------------------
#define LDT 40   // 32 + 8 pad (bf16 elems), 80B row stride
template<bool GELU, bool RES, bool WF32, bool WB16>
__global__ __launch_bounds__(256) void mfma_gemm_kernel(
    const unsigned short* __restrict__ A, const unsigned short* __restrict__ W,
    const float* __restrict__ bias, const float* __restrict__ res,
    float* __restrict__ outF, unsigned short* __restrict__ outB,
    int M, int N, int K)
{
    __shared__ unsigned short As[128 * LDT];
    __shared__ unsigned short Ws[128 * LDT];

    const int t    = threadIdx.x;
    const int m0   = blockIdx.x * 128;
    const int n0   = blockIdx.y * 128;
    const int wave = t >> 6, lane = t & 63;
    const int wr   = (wave >> 1) * 64, wc = (wave & 1) * 64;
    const int l15  = lane & 15, quad = lane >> 4;

    f32x4 acc[4][4];
#pragma unroll
    for (int i = 0; i < 4; i++)
#pragma unroll
        for (int j = 0; j < 4; j++)
#pragma unroll
            for (int r = 0; r < 4; r++) acc[i][j][r] = 0.0f;

    const int lr = t >> 1;          // staging row 0..127
    const int lk = (t & 1) * 16;    // staging k-offset 0 / 16
    const unsigned short* arow = A + (size_t)(m0 + lr) * K + lk;
    const unsigned short* wrow = W + (size_t)(n0 + lr) * K + lk;
    unsigned short* asd = &As[lr * LDT + lk];
    unsigned short* wsd = &Ws[lr * LDT + lk];

    for (int k0 = 0; k0 < K; k0 += 32) {
        us8v a0 = *(const us8v*)(arow + k0);
        us8v a1 = *(const us8v*)(arow + k0 + 8);
        us8v w0 = *(const us8v*)(wrow + k0);
        us8v w1 = *(const us8v*)(wrow + k0 + 8);
        __syncthreads();
        *(us8v*)(asd)     = a0; *(us8v*)(asd + 8) = a1;
        *(us8v*)(wsd)     = w0; *(us8v*)(wsd + 8) = w1;
        __syncthreads();

        short8 af[4], wf[4];
#pragma unroll
        for (int i = 0; i < 4; i++)
            af[i] = *(const short8*)&As[(wr + i * 16 + l15) * LDT + quad * 8];
#pragma unroll
        for (int j = 0; j < 4; j++)
            wf[j] = *(const short8*)&Ws[(wc + j * 16 + l15) * LDT + quad * 8];
#pragma unroll
        for (int i = 0; i < 4; i++)
#pragma unroll
            for (int j = 0; j < 4; j++)
                acc[i][j] = __builtin_amdgcn_mfma_f32_16x16x32_bf16(
                    af[i], wf[j], acc[i][j], 0, 0, 0);
    }

#pragma unroll
    for (int i = 0; i < 4; i++) {
        const int gr = m0 + wr + i * 16 + quad * 4;
#pragma unroll
        for (int j = 0; j < 4; j++) {
            const int gc = n0 + wc + j * 16 + l15;
            const float bv = bias[gc];
#pragma unroll
            for (int r = 0; r < 4; r++) {
                float v = acc[i][j][r] + bv;
                if (GELU) v = gelu_tanh(v);
                if (RES)  v += res[(size_t)(gr + r) * N + gc];
                if (WF32) outF[(size_t)(gr + r) * N + gc] = v;
                if (WB16) outB[(size_t)(gr + r) * N + gc] = f2b(v);
            }
        }
    }
}

// ---------------------------------------------------------------------------
// Patch-embed MFMA GEMM: A gathered from xb (bf16 image), W = conv_w bf16.
// out fp32 [M][256]. p = c*256 + ph*16 + pw; each 16-elt k-chunk is one
// contiguous 16-px patch row (32 B in bf16).
// ---------------------------------------------------------------------------
__global__ __launch_bounds__(256) void patch_mfma_kernel(
    const unsigned short* __restrict__ xb, const unsigned short* __restrict__ W,
    const float* __restrict__ bias, float* __restrict__ outF)
{
    __shared__ unsigned short As[128 * LDT];
    __shared__ unsigned short Ws[128 * LDT];

    const int t    = threadIdx.x;
    const int m0   = blockIdx.x * 128;
    const int n0   = blockIdx.y * 128;
    const int wave = t >> 6, lane = t & 63;
    const int wr   = (wave >> 1) * 64, wc = (wave & 1) * 64;
    const int l15  = lane & 15, quad = lane >> 4;

    f32x4 acc[4][4];
#pragma unroll
    for (int i = 0; i < 4; i++)
#pragma unroll
        for (int j = 0; j < 4; j++)
#pragma unroll
            for (int r = 0; r < 4; r++) acc[i][j][r] = 0.0f;

    const int lr = t >> 1;
    const int lk = (t & 1) * 16;
    const int m  = m0 + lr;
    const int b  = m >> 10;
    const int idx = m & 1023;
    const int hh = idx >> 5, ww = idx & 31;
    // base of this token's patch in xb (per channel-plane addressing below)
    const unsigned short* wrow = W + (size_t)(n0 + lr) * 768 + lk;
    unsigned short* asd = &As[lr * LDT + lk];
    unsigned short* wsd = &Ws[lr * LDT + lk];

    for (int k0 = 0; k0 < 768; k0 += 32) {
        const int p  = k0 + lk;          // pw == 0 always
        const int c  = p >> 8;
        const int ph = (p >> 4) & 15;
        const unsigned short* src =
            xb + (((size_t)(b * 3 + c) * 512) + (size_t)(hh * 16 + ph)) * 512 + ww * 16;
        us8v a0 = *(const us8v*)(src);
        us8v a1 = *(const us8v*)(src + 8);
        us8v w0 = *(const us8v*)(wrow + k0);
        us8v w1 = *(const us8v*)(wrow + k0 + 8);
        __syncthreads();
        *(us8v*)(asd)     = a0; *(us8v*)(asd + 8) = a1;
        *(us8v*)(wsd)     = w0; *(us8v*)(wsd + 8) = w1;
        __syncthreads();

        short8 af[4], wf[4];
#pragma unroll
        for (int i = 0; i < 4; i++)
            af[i] = *(const short8*)&As[(wr + i * 16 + l15) * LDT + quad * 8];
#pragma unroll
        for (int j = 0; j < 4; j++)
            wf[j] = *(const short8*)&Ws[(wc + j * 16 + l15) * LDT + quad * 8];
#pragma unroll
        for (int i = 0; i < 4; i++)
#pragma unroll
            for (int j = 0; j < 4; j++)
                acc[i][j] = __builtin_amdgcn_mfma_f32_16x16x32_bf16(
                    af[i], wf[j], acc[i][j], 0, 0, 0);
    }

#pragma unroll
    for (int i = 0; i < 4; i++) {
        const int gr = m0 + wr + i * 16 + quad * 4;
#pragma unroll
        for (int j = 0; j < 4; j++) {
            const int gc = n0 + wc + j * 16 + l15;
            const float bv = bias[gc];
#pragma unroll
            for (int r = 0; r < 4; r++)
                outF[(size_t)(gr + r) * 256 + gc] = acc[i][j][r] + bv;
        }
    }
}

// ---------------------------------------------------------------------------
// LayerNorm + sinusoidal PE. One block = one token (256 features).
// Writes fp32 (residual path) and bf16 (GEMM input).
// ---------------------------------------------------------------------------
__global__ __launch_bounds__(256) void ln_pe_kernel(
    const float* __restrict__ in, const float* __restrict__ w,
    const float* __restrict__ b, float* __restrict__ outF,
    unsigned short* __restrict__ outB)
{
    const int m = blockIdx.x;
    const int d = threadIdx.x;
    float v = in[(size_t)m * 256 + d];

    float s = v, s2 = v * v;
#pragma unroll
    for (int off = 32; off > 0; off >>= 1) {
        s  += __shfl_down(s,  off, 64);
        s2 += __shfl_down(s2, off, 64);
    }
    __shared__ float ss[4], ss2[4], stats[2];
    const int lane = d & 63, wid = d >> 6;
    if (lane == 0) { ss[wid] = s; ss2[wid] = s2; }
    __syncthreads();
    if (d == 0) {
        float a  = ss[0] + ss[1] + ss[2] + ss[3];
        float a2 = ss2[0] + ss2[1] + ss2[2] + ss2[3];
        float mean = a * (1.0f / 256.0f);
        float var  = a2 * (1.0f / 256.0f) - mean * mean;
        stats[0] = mean;
        stats[1] = rsqrtf(var + 1e-5f);
    }
    __syncthreads();
    const float mean = stats[0], rstd = stats[1];

    const int pos = m & 1023;
    const int ieven = d & ~1;
    float div = expf(-9.210340371976184f * (float)ieven * (1.0f / 256.0f));
    float ang = (float)pos * div;
    float pe = (d & 1) ? cosf(ang) : sinf(ang);

    float o = (v - mean) * rstd * w[d] + b[d] + pe;
    outF[(size_t)m * 256 + d] = o;
    outB[(size_t)m * 256 + d] = f2b(o);
}

// ---------------------------------------------------------------------------
// Windowed attention: qkv bf16 [32768][768] -> out bf16 [32768][256].
// One block = one (batch, window, head); fp32 compute in LDS.
// ---------------------------------------------------------------------------
__global__ __launch_bounds__(256) void attn_kernel(
    const unsigned short* __restrict__ qkv, unsigned short* __restrict__ out)
{
    const int blk = blockIdx.x;        // 0..4095
    const int h = blk & 7;
    const int w = (blk >> 3) & 15;
    const int b = blk >> 7;
    const int m_base = b * 1024 + w * 64;

    __shared__ float Q[64][33], Kt[64][33], V[64][33];
    __shared__ float S[64][65];

    const int t = threadIdx.x;
    {   // loads: row = t>>2, 8 elems at c0=(t&3)*8 per matrix
        const int row = t >> 2;
        const int c0 = (t & 3) * 8;
        const unsigned short* base = qkv + (size_t)(m_base + row) * 768 + h * 32 + c0;
        us8v q0 = *(const us8v*)(base);
        us8v k0 = *(const us8v*)(base + 256);
        us8v v0 = *(const us8v*)(base + 512);
#pragma unroll
        for (int j = 0; j < 8; j++) {
            Q [row][c0 + j] = b2f(q0[j]);
            Kt[row][c0 + j] = b2f(k0[j]);
            V [row][c0 + j] = b2f(v0[j]);
        }
    }
    __syncthreads();

    {   // scores: thread handles row qi = t>>2, 16 cols starting (t&3)*16
        const int qi = t >> 2;
        const int kb = (t & 3) * 16;
        const float scale = 0.17677669529663687f; // 1/sqrt(32)
        float qreg[32];
#pragma unroll
        for (int i = 0; i < 32; i++) qreg[i] = Q[qi][i];
        for (int kk = 0; kk < 16; kk++) {
            const int ki = kb + kk;
            float a = 0.0f;
#pragma unroll
            for (int i = 0; i < 32; i++) a = fmaf(qreg[i], Kt[ki][i], a);
            S[qi][ki] = a * scale;
        }
    }
    __syncthreads();

    if (t < 64) {   // softmax over row t
        float mx = -1e30f;
        for (int k = 0; k < 64; k++) mx = fmaxf(mx, S[t][k]);
        float sum = 0.0f;
        for (int k = 0; k < 64; k++) { float e = expf(S[t][k] - mx); S[t][k] = e; sum += e; }
        float inv = 1.0f / sum;
        for (int k = 0; k < 64; k++) S[t][k] *= inv;
    }
    __syncthreads();

    {   // out: thread handles row qi = t&63, 8 cols at i0=(t>>6)*8
        const int qi = t & 63;
        const int i0 = (t >> 6) * 8;
        float acc[8];
#pragma unroll
        for (int j = 0; j < 8; j++) acc[j] = 0.0f;
        for (int k = 0; k < 64; k++) {
            float s = S[qi][k];
#pragma unroll
            for (int j = 0; j < 8; j++) acc[j] = fmaf(s, V[k][i0 + j], acc[j]);
        }
        unsigned short* dst = out + (size_t)(m_base + qi) * 256 + h * 32 + i0;
        us8v o;
#pragma unroll
        for (int j = 0; j < 8; j++) o[j] = f2b(acc[j]);
        *(us8v*)dst = o;
    }
}

// ---------------------------------------------------------------------------
// Workspace layout (bytes), total ~186.5 MB:
//   SLOT_A  @ 0          (67.1MB): xb (K0a..K1) -> hidden bf16 (K3..K4, K8..K9)
//   SLOT_B  @ 67108864   (50.3MB): h0 fp32 (K1..K2) -> qkv bf16 (K5..K6)
//   h1f     @ 117440512  (33.6MB): fp32 residual (K2..K7)
//   SLOT_C  @ 150994944  (16.8MB): h1 bf16 (K2..K3) -> attn-out bf16 (K6..K7)
//   SLOT_D  @ 167772160  (16.8MB): ffn1-out bf16 (K4..K5) -> h2 bf16 (K7..K8)
//   weights @ 184549376  (~2MB):   bf16 conv_w, qkv_w, proj_w, ff_w1, ff_w2
// ---------------------------------------------------------------------------
extern "C" void kernel_launch(void* const* d_in, const int* in_sizes, int n_in,
                              void* d_out, int out_size, void* d_ws, size_t ws_size,
                              hipStream_t stream)
{
    const float* x      = (const float*)d_in[0];
    const float* conv_w = (const float*)d_in[1];
    const float* conv_b = (const float*)d_in[2];
    const float* ln_w   = (const float*)d_in[3];
    const float* ln_b   = (const float*)d_in[4];
    const float* qkv_w  = (const float*)d_in[5];
    const float* qkv_b  = (const float*)d_in[6];
    const float* proj_w = (const float*)d_in[7];
    const float* proj_b = (const float*)d_in[8];
    const float* ff_w1  = (const float*)d_in[9];
    const float* ff_b1  = (const float*)d_in[10];
    const float* ff_w2  = (const float*)d_in[11];
    const float* ff_b2  = (const float*)d_in[12];
    float* out = (float*)d_out;

    char* ws = (char*)d_ws;
    unsigned short* xb    = (unsigned short*)(ws);                 // SLOT_A
    unsigned short* hidb  = (unsigned short*)(ws);                 // SLOT_A reuse
    float*          h0    = (float*)(ws + 67108864);               // SLOT_B
    unsigned short* qkvb  = (unsigned short*)(ws + 67108864);      // SLOT_B reuse
    float*          h1f   = (float*)(ws + 117440512);
    unsigned short* h1b   = (unsigned short*)(ws + 150994944);     // SLOT_C
    unsigned short* aob   = (unsigned short*)(ws + 150994944);     // SLOT_C reuse
    unsigned short* f1b   = (unsigned short*)(ws + 167772160);     // SLOT_D
    unsigned short* h2b   = (unsigned short*)(ws + 167772160);     // SLOT_D reuse
    unsigned short* wbase = (unsigned short*)(ws + 184549376);
    unsigned short* conv_wb = wbase;                 // 196608
    unsigned short* qkv_wb  = wbase + 196608;        // 196608
    unsigned short* proj_wb = wbase + 393216;        // 65536
    unsigned short* ff_w1b  = wbase + 458752;        // 262144
    unsigned short* ff_w2b  = wbase + 720896;        // 262144

    const int M = M_TOK;
    dim3 blk(256);

    // K0: conversions
    cvt_f2b_kernel<<<dim3(25165824 / 1024), blk, 0, stream>>>(x, xb, 25165824);
    cvt_f2b_kernel<<<dim3(196608 / 1024), blk, 0, stream>>>(conv_w, conv_wb, 196608);
    cvt_f2b_kernel<<<dim3(196608 / 1024), blk, 0, stream>>>(qkv_w, qkv_wb, 196608);
    cvt_f2b_kernel<<<dim3(65536 / 1024), blk, 0, stream>>>(proj_w, proj_wb, 65536);
    cvt_f2b_kernel<<<dim3(262144 / 1024), blk, 0, stream>>>(ff_w1, ff_w1b, 262144);
    cvt_f2b_kernel<<<dim3(262144 / 1024), blk, 0, stream>>>(ff_w2, ff_w2b, 262144);

    // K1: patch embed -> h0 (fp32)
    patch_mfma_kernel<<<dim3(M / 128, 2), blk, 0, stream>>>(xb, conv_wb, conv_b, h0);
    // K2: LN + PE -> h1f (fp32 residual) + h1b (bf16)
    ln_pe_kernel<<<dim3(M), blk, 0, stream>>>(h0, ln_w, ln_b, h1f, h1b);
    // K3: FFN1a: gelu(h1 @ w1^T + b1) -> hidb (bf16)
    mfma_gemm_kernel<true, false, false, true><<<dim3(M / 128, 8), blk, 0, stream>>>(
        h1b, ff_w1b, ff_b1, nullptr, nullptr, hidb, M, 1024, 256);
    // K4: FFN1b: hidb @ w2^T + b2 -> f1b (bf16)
    mfma_gemm_kernel<false, false, false, true><<<dim3(M / 128, 2), blk, 0, stream>>>(
        hidb, ff_w2b, ff_b2, nullptr, nullptr, f1b, M, 256, 1024);
    // K5: qkv: f1b @ qkv_w^T + qkv_b -> qkvb (bf16)
    mfma_gemm_kernel<false, false, false, true><<<dim3(M / 128, 6), blk, 0, stream>>>(
        f1b, qkv_wb, qkv_b, nullptr, nullptr, qkvb, M, 768, 256);
    // K6: windowed attention: qkvb -> aob (bf16)
    attn_kernel<<<dim3(4096), blk, 0, stream>>>(qkvb, aob);
    // K7: proj + residual(h1f): aob @ proj_w^T + proj_b + h1f -> out (fp32) + h2b (bf16)
    mfma_gemm_kernel<false, true, true, true><<<dim3(M / 128, 2), blk, 0, stream>>>(
        aob, proj_wb, proj_b, h1f, out, h2b, M, 256, 256);
    // K8: FFN2a: gelu(h2b @ w1^T + b1) -> hidb (bf16)
    mfma_gemm_kernel<true, false, false, true><<<dim3(M / 128, 8), blk, 0, stream>>>(
        h2b, ff_w1b, ff_b1, nullptr, nullptr, hidb, M, 1024, 256);
    // K9: FFN2b + final residual: hidb @ w2^T + b2 + out -> out (fp32)
    mfma_gemm_kernel<false, true, true, false><<<dim3(M / 128, 2), blk, 0, stream>>>(
        hidb, ff_w2b, ff_b2, out, out, nullptr, M, 256, 1024);
}

// Round 3
// 471.658 us; speedup vs baseline: 4.6050x; 1.1869x over previous
//
#include <hip/hip_runtime.h>
#include <math.h>

// ============================================================================
// ViT block on MI355X — Round 3:
//   * GEMMs: m97-style global_load_lds(16B) staging, unpadded LDS [128][32].
//   * Attention: MFMA (QK^T + softmax-in-registers + LDS P/V^T + PV).
// B=32, C=3, H=W=512, P=16 -> M=32768 tokens, D=256, HF=1024.
// ============================================================================

#define M_TOK 32768

typedef __attribute__((ext_vector_type(8))) short  short8;   // 8 bf16 (4 VGPRs)
typedef __attribute__((ext_vector_type(4))) float  f32x4;
typedef __attribute__((ext_vector_type(8))) unsigned short us8v;
typedef __attribute__((ext_vector_type(4))) unsigned short us4v;

__device__ __forceinline__ unsigned short f2b(float f) {
    union { float f; unsigned u; } c; c.f = f;
    unsigned r = c.u + 0x7fffu + ((c.u >> 16) & 1u);   // RNE
    return (unsigned short)(r >> 16);
}
__device__ __forceinline__ float gelu_tanh(float x) {
    const float c0 = 0.7978845608028654f; // sqrt(2/pi)
    float inner = c0 * (x + 0.044715f * x * x * x);
    return 0.5f * x * (1.0f + tanhf(inner));
}
// async global->LDS, 16B per lane; lds dest must be wave-uniform base (+lane*16 by HW)
__device__ __forceinline__ void load_lds16(const unsigned short* g, void* lds) {
    __builtin_amdgcn_global_load_lds(
        (const __attribute__((address_space(1))) unsigned int*)g,
        (__attribute__((address_space(3))) unsigned int*)lds, 16, 0, 0);
}

// ---------------------------------------------------------------------------
// fp32 -> bf16 convert (n % 4 == 0)
// ---------------------------------------------------------------------------
__global__ __launch_bounds__(256) void cvt_f2b_kernel(
    const float* __restrict__ in, unsigned short* __restrict__ out, int n)
{
    int i = (blockIdx.x * 256 + threadIdx.x) * 4;
    if (i >= n) return;
    float4 v = *(const float4*)(in + i);
    us4v o;
    o[0] = f2b(v.x); o[1] = f2b(v.y); o[2] = f2b(v.z); o[3] = f2b(v.w);
    *(us4v*)(out + i) = o;
}

// ---------------------------------------------------------------------------
// MFMA GEMM (m97 staging): C = A (MxK) . W^T (NxK) + bias (+gelu/res)
// 128x128 tile, BK=32, 256 thr = 4 waves 2x2. LDS unpadded [128][32] bf16.
// ---------------------------------------------------------------------------
template<bool GELU, bool RES, bool WF32, bool WB16>
__global__ __launch_bounds__(256) void mfma_gemm_kernel(
    const unsigned short* __restrict__ A, const unsigned short* __restrict__ W,
    const float* __restrict__ bias, const float* __restrict__ res,
    float* __restrict__ outF, unsigned short* __restrict__ outB,
    int M, int N, int K)
{
    __shared__ unsigned short As[128 * 32];
    __shared__ unsigned short Ws[128 * 32];

    const int t    = threadIdx.x;
    const int m0   = blockIdx.x * 128;
    const int n0   = blockIdx.y * 128;
    const int wv   = t >> 6, lane = t & 63;
    const int wr   = (wv >> 1) * 64, wc = (wv & 1) * 64;
    const int l15  = lane & 15, quad = lane >> 4;

    f32x4 acc[4][4];
#pragma unroll
    for (int i = 0; i < 4; i++)
#pragma unroll
        for (int j = 0; j < 4; j++)
#pragma unroll
            for (int r = 0; r < 4; r++) acc[i][j][r] = 0.0f;

    // staging map: set s covers rows s*64 + wv*16 + (lane>>2), k-chunk (lane&3)*8
    const int srow = wv * 16 + (lane >> 2);
    const int skk  = (lane & 3) * 8;
    const unsigned short* gA0 = A + (size_t)(m0 + srow) * K + skk;
    const unsigned short* gA1 = gA0 + (size_t)64 * K;
    const unsigned short* gW0 = W + (size_t)(n0 + srow) * K + skk;
    const unsigned short* gW1 = gW0 + (size_t)64 * K;
    char* lA0 = (char*)As + wv * 1024;
    char* lA1 = lA0 + 4096;
    char* lW0 = (char*)Ws + wv * 1024;
    char* lW1 = lW0 + 4096;

    for (int k0 = 0; k0 < K; k0 += 32) {
        __syncthreads();                 // prior iter's ds_reads done
        load_lds16(gA0 + k0, lA0);
        load_lds16(gA1 + k0, lA1);
        load_lds16(gW0 + k0, lW0);
        load_lds16(gW1 + k0, lW1);
        __syncthreads();                 // drains vmcnt -> LDS visible

        short8 af[4], wf[4];
#pragma unroll
        for (int i = 0; i < 4; i++)
            af[i] = *(const short8*)&As[(wr + i * 16 + l15) * 32 + quad * 8];
#pragma unroll
        for (int j = 0; j < 4; j++)
            wf[j] = *(const short8*)&Ws[(wc + j * 16 + l15) * 32 + quad * 8];
#pragma unroll
        for (int i = 0; i < 4; i++)
#pragma unroll
            for (int j = 0; j < 4; j++)
                acc[i][j] = __builtin_amdgcn_mfma_f32_16x16x32_bf16(
                    af[i], wf[j], acc[i][j], 0, 0, 0);
    }

#pragma unroll
    for (int i = 0; i < 4; i++) {
        const int gr = m0 + wr + i * 16 + quad * 4;
#pragma unroll
        for (int j = 0; j < 4; j++) {
            const int gc = n0 + wc + j * 16 + l15;
            const float bv = bias[gc];
#pragma unroll
            for (int r = 0; r < 4; r++) {
                float v = acc[i][j][r] + bv;
                if (GELU) v = gelu_tanh(v);
                if (RES)  v += res[(size_t)(gr + r) * N + gc];
                if (WF32) outF[(size_t)(gr + r) * N + gc] = v;
                if (WB16) outB[(size_t)(gr + r) * N + gc] = f2b(v);
            }
        }
    }
}

// ---------------------------------------------------------------------------
// Patch-embed MFMA GEMM: A gathered from bf16 image xb, W = conv_w bf16.
// Same m97 staging; A's per-lane global addresses are gathered patch rows
// (each 8-elem k-chunk = 8 contiguous pixels, never straddles a patch row).
// ---------------------------------------------------------------------------
__global__ __launch_bounds__(256) void patch_mfma_kernel(
    const unsigned short* __restrict__ xb, const unsigned short* __restrict__ W,
    const float* __restrict__ bias, float* __restrict__ outF)
{
    __shared__ unsigned short As[128 * 32];
    __shared__ unsigned short Ws[128 * 32];

    const int t    = threadIdx.x;
    const int m0   = blockIdx.x * 128;
    const int n0   = blockIdx.y * 128;
    const int wv   = t >> 6, lane = t & 63;
    const int wr   = (wv >> 1) * 64, wc = (wv & 1) * 64;
    const int l15  = lane & 15, quad = lane >> 4;

    f32x4 acc[4][4];
#pragma unroll
    for (int i = 0; i < 4; i++)
#pragma unroll
        for (int j = 0; j < 4; j++)
#pragma unroll
            for (int r = 0; r < 4; r++) acc[i][j][r] = 0.0f;

    const int srow = wv * 16 + (lane >> 2);
    const int skk  = (lane & 3) * 8;   // k-offset within BK: 0,8,16,24
    // token for set 0 / set 1
    size_t xoff[2];
#pragma unroll
    for (int s = 0; s < 2; s++) {
        const int m  = m0 + s * 64 + srow;
        const int b  = m >> 10;
        const int idx = m & 1023;
        const int hh = idx >> 5, ww = idx & 31;
        xoff[s] = ((size_t)(b * 3) * 512 + (size_t)(hh * 16)) * 512 + ww * 16;
    }
    const unsigned short* gW0 = W + (size_t)(n0 + srow) * 768 + skk;
    const unsigned short* gW1 = gW0 + (size_t)64 * 768;
    char* lA0 = (char*)As + wv * 1024;
    char* lA1 = lA0 + 4096;
    char* lW0 = (char*)Ws + wv * 1024;
    char* lW1 = lW0 + 4096;

    for (int k0 = 0; k0 < 768; k0 += 32) {
        const int k  = k0 + skk;
        const int c  = k >> 8;
        const int ph = (k >> 4) & 15;
        const int pw = k & 15;          // 0 or 8
        const size_t koff = (size_t)c * 262144 + (size_t)ph * 512 + pw;
        __syncthreads();
        load_lds16(xb + xoff[0] + koff, lA0);
        load_lds16(xb + xoff[1] + koff, lA1);
        load_lds16(gW0 + k0, lW0);
        load_lds16(gW1 + k0, lW1);
        __syncthreads();

        short8 af[4], wf[4];
#pragma unroll
        for (int i = 0; i < 4; i++)
            af[i] = *(const short8*)&As[(wr + i * 16 + l15) * 32 + quad * 8];
#pragma unroll
        for (int j = 0; j < 4; j++)
            wf[j] = *(const short8*)&Ws[(wc + j * 16 + l15) * 32 + quad * 8];
#pragma unroll
        for (int i = 0; i < 4; i++)
#pragma unroll
            for (int j = 0; j < 4; j++)
                acc[i][j] = __builtin_amdgcn_mfma_f32_16x16x32_bf16(
                    af[i], wf[j], acc[i][j], 0, 0, 0);
    }

#pragma unroll
    for (int i = 0; i < 4; i++) {
        const int gr = m0 + wr + i * 16 + quad * 4;
#pragma unroll
        for (int j = 0; j < 4; j++) {
            const int gc = n0 + wc + j * 16 + l15;
            const float bv = bias[gc];
#pragma unroll
            for (int r = 0; r < 4; r++)
                outF[(size_t)(gr + r) * 256 + gc] = acc[i][j][r] + bv;
        }
    }
}

// ---------------------------------------------------------------------------
// LayerNorm + sinusoidal PE. One block = one token (256 features).
// ---------------------------------------------------------------------------
__global__ __launch_bounds__(256) void ln_pe_kernel(
    const float* __restrict__ in, const float* __restrict__ w,
    const float* __restrict__ b, float* __restrict__ outF,
    unsigned short* __restrict__ outB)
{
    const int m = blockIdx.x;
    const int d = threadIdx.x;
    float v = in[(size_t)m * 256 + d];

    float s = v, s2 = v * v;
#pragma unroll
    for (int off = 32; off > 0; off >>= 1) {
        s  += __shfl_down(s,  off, 64);
        s2 += __shfl_down(s2, off, 64);
    }
    __shared__ float ss[4], ss2[4], stats[2];
    const int lane = d & 63, wid = d >> 6;
    if (lane == 0) { ss[wid] = s; ss2[wid] = s2; }
    __syncthreads();
    if (d == 0) {
        float a  = ss[0] + ss[1] + ss[2] + ss[3];
        float a2 = ss2[0] + ss2[1] + ss2[2] + ss2[3];
        float mean = a * (1.0f / 256.0f);
        float var  = a2 * (1.0f / 256.0f) - mean * mean;
        stats[0] = mean;
        stats[1] = rsqrtf(var + 1e-5f);
    }
    __syncthreads();
    const float mean = stats[0], rstd = stats[1];

    const int pos = m & 1023;
    const int ieven = d & ~1;
    float div = expf(-9.210340371976184f * (float)ieven * (1.0f / 256.0f));
    float ang = (float)pos * div;
    float pe = (d & 1) ? cosf(ang) : sinf(ang);

    float o = (v - mean) * rstd * w[d] + b[d] + pe;
    outF[(size_t)m * 256 + d] = o;
    outB[(size_t)m * 256 + d] = f2b(o);
}

// ---------------------------------------------------------------------------
// MFMA windowed attention. One block = one (batch, window, head).
// 4 waves, wave wv owns Q-row strip [wv*16, wv*16+16).
// QK^T: both operands [row][k] contiguous from global (no transpose).
// Softmax in C-layout registers. P and V^T round-trip through LDS (m120).
// ---------------------------------------------------------------------------
__global__ __launch_bounds__(256) void attn_mfma_kernel(
    const unsigned short* __restrict__ qkv, unsigned short* __restrict__ out)
{
    __shared__ unsigned short Ps[64 * 72];   // P, stride 72 (b128-aligned, padded)
    __shared__ unsigned short Vt[32 * 72];   // V^T [headdim][key]

    const int blk = blockIdx.x;        // 0..4095
    const int h = blk & 7;
    const int w = (blk >> 3) & 15;
    const int b = blk >> 7;
    const int m_base = b * 1024 + w * 64;

    const int t = threadIdx.x;
    const int wv = t >> 6, lane = t & 63;
    const int l15 = lane & 15, quad = lane >> 4;

    // ---- stage V^T (cooperative, 8 elems/thread) ----
    {
        const int row = t >> 2;             // key 0..63
        const int c0  = (t & 3) * 8;        // headdim chunk
        const unsigned short* src = qkv + (size_t)(m_base + row) * 768 + 512 + h * 32 + c0;
        us8v v = *(const us8v*)src;
#pragma unroll
        for (int j = 0; j < 8; j++) Vt[(c0 + j) * 72 + row] = v[j];
    }

    // ---- QK^T: S strip (16x64) = 4 MFMAs ----
    short8 aq = *(const short8*)(qkv + (size_t)(m_base + wv * 16 + l15) * 768 + h * 32 + quad * 8);
    f32x4 c[4];
#pragma unroll
    for (int j = 0; j < 4; j++) {
        short8 bk = *(const short8*)(qkv + (size_t)(m_base + j * 16 + l15) * 768 + 256 + h * 32 + quad * 8);
        f32x4 z = {0.0f, 0.0f, 0.0f, 0.0f};
        c[j] = __builtin_amdgcn_mfma_f32_16x16x32_bf16(aq, bk, z, 0, 0, 0);
    }

    // ---- softmax over keys (row = quad*4+reg, col = j*16+l15) ----
    const float scale = 0.17677669529663687f; // 1/sqrt(32)
    float mx[4], sm[4];
#pragma unroll
    for (int r = 0; r < 4; r++) {
        float m0 = -1e30f;
#pragma unroll
        for (int j = 0; j < 4; j++) { c[j][r] *= scale; m0 = fmaxf(m0, c[j][r]); }
#pragma unroll
        for (int d = 1; d < 16; d <<= 1) m0 = fmaxf(m0, __shfl_xor(m0, d, 64));
        mx[r] = m0;
        float s0 = 0.0f;
#pragma unroll
        for (int j = 0; j < 4; j++) { float e = __expf(c[j][r] - m0); c[j][r] = e; s0 += e; }
#pragma unroll
        for (int d = 1; d < 16; d <<= 1) s0 += __shfl_xor(s0, d, 64);
        sm[r] = 1.0f / s0;
    }

    // ---- write P (bf16) to LDS ----
#pragma unroll
    for (int r = 0; r < 4; r++) {
        const int prow = wv * 16 + quad * 4 + r;
#pragma unroll
        for (int j = 0; j < 4; j++)
            Ps[prow * 72 + j * 16 + l15] = f2b(c[j][r] * sm[r]);
    }
    __syncthreads();

    // ---- PV: O strip (16x32) = 4 MFMAs ----
    short8 ap0 = *(const short8*)&Ps[(wv * 16 + l15) * 72 + quad * 8];
    short8 ap1 = *(const short8*)&Ps[(wv * 16 + l15) * 72 + 32 + quad * 8];
    f32x4 o[2];
#pragma unroll
    for (int nt = 0; nt < 2; nt++) {
        short8 bv0 = *(const short8*)&Vt[(nt * 16 + l15) * 72 + quad * 8];
        short8 bv1 = *(const short8*)&Vt[(nt * 16 + l15) * 72 + 32 + quad * 8];
        f32x4 z = {0.0f, 0.0f, 0.0f, 0.0f};
        o[nt] = __builtin_amdgcn_mfma_f32_16x16x32_bf16(ap0, bv0, z, 0, 0, 0);
        o[nt] = __builtin_amdgcn_mfma_f32_16x16x32_bf16(ap1, bv1, o[nt], 0, 0, 0);
    }

    // ---- write O (bf16) ----
#pragma unroll
    for (int nt = 0; nt < 2; nt++) {
#pragma unroll
        for (int r = 0; r < 4; r++) {
            const int row = m_base + wv * 16 + quad * 4 + r;
            out[(size_t)row * 256 + h * 32 + nt * 16 + l15] = f2b(o[nt][r]);
        }
    }
}

// ---------------------------------------------------------------------------
// Workspace layout (bytes), total ~186.5 MB (same as round 2).
// ---------------------------------------------------------------------------
extern "C" void kernel_launch(void* const* d_in, const int* in_sizes, int n_in,
                              void* d_out, int out_size, void* d_ws, size_t ws_size,
                              hipStream_t stream)
{
    const float* x      = (const float*)d_in[0];
    const float* conv_w = (const float*)d_in[1];
    const float* conv_b = (const float*)d_in[2];
    const float* ln_w   = (const float*)d_in[3];
    const float* ln_b   = (const float*)d_in[4];
    const float* qkv_w  = (const float*)d_in[5];
    const float* qkv_b  = (const float*)d_in[6];
    const float* proj_w = (const float*)d_in[7];
    const float* proj_b = (const float*)d_in[8];
    const float* ff_w1  = (const float*)d_in[9];
    const float* ff_b1  = (const float*)d_in[10];
    const float* ff_w2  = (const float*)d_in[11];
    const float* ff_b2  = (const float*)d_in[12];
    float* out = (float*)d_out;

    char* ws = (char*)d_ws;
    unsigned short* xb    = (unsigned short*)(ws);                 // SLOT_A
    unsigned short* hidb  = (unsigned short*)(ws);                 // SLOT_A reuse
    float*          h0    = (float*)(ws + 67108864);               // SLOT_B
    unsigned short* qkvb  = (unsigned short*)(ws + 67108864);      // SLOT_B reuse
    float*          h1f   = (float*)(ws + 117440512);
    unsigned short* h1b   = (unsigned short*)(ws + 150994944);     // SLOT_C
    unsigned short* aob   = (unsigned short*)(ws + 150994944);     // SLOT_C reuse
    unsigned short* f1b   = (unsigned short*)(ws + 167772160);     // SLOT_D
    unsigned short* h2b   = (unsigned short*)(ws + 167772160);     // SLOT_D reuse
    unsigned short* wbase = (unsigned short*)(ws + 184549376);
    unsigned short* conv_wb = wbase;                 // 196608
    unsigned short* qkv_wb  = wbase + 196608;        // 196608
    unsigned short* proj_wb = wbase + 393216;        // 65536
    unsigned short* ff_w1b  = wbase + 458752;        // 262144
    unsigned short* ff_w2b  = wbase + 720896;        // 262144

    const int M = M_TOK;
    dim3 blk(256);

    // K0: conversions
    cvt_f2b_kernel<<<dim3(25165824 / 1024), blk, 0, stream>>>(x, xb, 25165824);
    cvt_f2b_kernel<<<dim3(196608 / 1024), blk, 0, stream>>>(conv_w, conv_wb, 196608);
    cvt_f2b_kernel<<<dim3(196608 / 1024), blk, 0, stream>>>(qkv_w, qkv_wb, 196608);
    cvt_f2b_kernel<<<dim3(65536 / 1024), blk, 0, stream>>>(proj_w, proj_wb, 65536);
    cvt_f2b_kernel<<<dim3(262144 / 1024), blk, 0, stream>>>(ff_w1, ff_w1b, 262144);
    cvt_f2b_kernel<<<dim3(262144 / 1024), blk, 0, stream>>>(ff_w2, ff_w2b, 262144);

    // K1: patch embed -> h0 (fp32)
    patch_mfma_kernel<<<dim3(M / 128, 2), blk, 0, stream>>>(xb, conv_wb, conv_b, h0);
    // K2: LN + PE -> h1f (fp32 residual) + h1b (bf16)
    ln_pe_kernel<<<dim3(M), blk, 0, stream>>>(h0, ln_w, ln_b, h1f, h1b);
    // K3: FFN1a: gelu(h1 @ w1^T + b1) -> hidb (bf16)
    mfma_gemm_kernel<true, false, false, true><<<dim3(M / 128, 8), blk, 0, stream>>>(
        h1b, ff_w1b, ff_b1, nullptr, nullptr, hidb, M, 1024, 256);
    // K4: FFN1b: hidb @ w2^T + b2 -> f1b (bf16)
    mfma_gemm_kernel<false, false, false, true><<<dim3(M / 128, 2), blk, 0, stream>>>(
        hidb, ff_w2b, ff_b2, nullptr, nullptr, f1b, M, 256, 1024);
    // K5: qkv: f1b @ qkv_w^T + qkv_b -> qkvb (bf16)
    mfma_gemm_kernel<false, false, false, true><<<dim3(M / 128, 6), blk, 0, stream>>>(
        f1b, qkv_wb, qkv_b, nullptr, nullptr, qkvb, M, 768, 256);
    // K6: windowed attention (MFMA): qkvb -> aob (bf16)
    attn_mfma_kernel<<<dim3(4096), blk, 0, stream>>>(qkvb, aob);
    // K7: proj + residual(h1f): aob @ proj_w^T + proj_b + h1f -> out + h2b
    mfma_gemm_kernel<false, true, true, true><<<dim3(M / 128, 2), blk, 0, stream>>>(
        aob, proj_wb, proj_b, h1f, out, h2b, M, 256, 256);
    // K8: FFN2a: gelu(h2b @ w1^T + b1) -> hidb (bf16)
    mfma_gemm_kernel<true, false, false, true><<<dim3(M / 128, 8), blk, 0, stream>>>(
        h2b, ff_w1b, ff_b1, nullptr, nullptr, hidb, M, 1024, 256);
    // K9: FFN2b + final residual: hidb @ w2^T + b2 + out -> out
    mfma_gemm_kernel<false, true, true, false><<<dim3(M / 128, 2), blk, 0, stream>>>(
        hidb, ff_w2b, ff_b2, out, out, nullptr, M, 256, 1024);
}

// Round 4
// 436.398 us; speedup vs baseline: 4.9770x; 1.0808x over previous
//
#include <hip/hip_runtime.h>
#include <math.h>

// ============================================================================
// ViT block on MI355X — Round 4:
//   * GELU via sigmoid identity + __expf/v_rcp (kills libcall tanhf epilogue).
//   * Sinusoidal PE precomputed into a 1MB table (kills sinf/cosf in ln_pe).
//   * GEMMs/attention otherwise as round 3 (m97 staging, MFMA attention).
// ============================================================================

#define M_TOK 32768

typedef __attribute__((ext_vector_type(8))) short  short8;   // 8 bf16 (4 VGPRs)
typedef __attribute__((ext_vector_type(4))) float  f32x4;
typedef __attribute__((ext_vector_type(8))) unsigned short us8v;
typedef __attribute__((ext_vector_type(4))) unsigned short us4v;

__device__ __forceinline__ unsigned short f2b(float f) {
    union { float f; unsigned u; } c; c.f = f;
    unsigned r = c.u + 0x7fffu + ((c.u >> 16) & 1u);   // RNE
    return (unsigned short)(r >> 16);
}
__device__ __forceinline__ float gelu_fast(float x) {
    // 0.5x(1+tanh(c0(x+0.044715x^3))) == x * sigmoid(2*c0*(x+0.044715x^3))
    const float c0 = 0.7978845608028654f;            // sqrt(2/pi)
    const float c1 = 0.044715f * 0.7978845608028654f;
    float z = x * (c0 + c1 * x * x);
    float e = __expf(-2.0f * z);
    return x * __builtin_amdgcn_rcpf(1.0f + e);
}
// async global->LDS, 16B per lane; lds dest must be wave-uniform base (+lane*16 by HW)
__device__ __forceinline__ void load_lds16(const unsigned short* g, void* lds) {
    __builtin_amdgcn_global_load_lds(
        (const __attribute__((address_space(1))) unsigned int*)g,
        (__attribute__((address_space(3))) unsigned int*)lds, 16, 0, 0);
}

// ---------------------------------------------------------------------------
// fp32 -> bf16 convert (n % 4 == 0)
// ---------------------------------------------------------------------------
__global__ __launch_bounds__(256) void cvt_f2b_kernel(
    const float* __restrict__ in, unsigned short* __restrict__ out, int n)
{
    int i = (blockIdx.x * 256 + threadIdx.x) * 4;
    if (i >= n) return;
    float4 v = *(const float4*)(in + i);
    us4v o;
    o[0] = f2b(v.x); o[1] = f2b(v.y); o[2] = f2b(v.z); o[3] = f2b(v.w);
    *(us4v*)(out + i) = o;
}

// ---------------------------------------------------------------------------
// Sinusoidal PE table: pe[pos][d], pos<1024, d<256. Run once per launch
// (262144 elems — libcall cost negligible here).
// ---------------------------------------------------------------------------
__global__ __launch_bounds__(256) void pe_init_kernel(float* __restrict__ pe)
{
    const int pos = blockIdx.x;
    const int d   = threadIdx.x;
    const int ieven = d & ~1;
    float div = expf(-9.210340371976184f * (float)ieven * (1.0f / 256.0f));
    float ang = (float)pos * div;
    pe[pos * 256 + d] = (d & 1) ? cosf(ang) : sinf(ang);
}

// ---------------------------------------------------------------------------
// MFMA GEMM (m97 staging): C = A (MxK) . W^T (NxK) + bias (+gelu/res)
// 128x128 tile, BK=32, 256 thr = 4 waves 2x2. LDS unpadded [128][32] bf16.
// ---------------------------------------------------------------------------
template<bool GELU, bool RES, bool WF32, bool WB16>
__global__ __launch_bounds__(256) void mfma_gemm_kernel(
    const unsigned short* __restrict__ A, const unsigned short* __restrict__ W,
    const float* __restrict__ bias, const float* __restrict__ res,
    float* __restrict__ outF, unsigned short* __restrict__ outB,
    int M, int N, int K)
{
    __shared__ unsigned short As[128 * 32];
    __shared__ unsigned short Ws[128 * 32];

    const int t    = threadIdx.x;
    const int m0   = blockIdx.x * 128;
    const int n0   = blockIdx.y * 128;
    const int wv   = t >> 6, lane = t & 63;
    const int wr   = (wv >> 1) * 64, wc = (wv & 1) * 64;
    const int l15  = lane & 15, quad = lane >> 4;

    f32x4 acc[4][4];
#pragma unroll
    for (int i = 0; i < 4; i++)
#pragma unroll
        for (int j = 0; j < 4; j++)
#pragma unroll
            for (int r = 0; r < 4; r++) acc[i][j][r] = 0.0f;

    // staging map: set s covers rows s*64 + wv*16 + (lane>>2), k-chunk (lane&3)*8
    const int srow = wv * 16 + (lane >> 2);
    const int skk  = (lane & 3) * 8;
    const unsigned short* gA0 = A + (size_t)(m0 + srow) * K + skk;
    const unsigned short* gA1 = gA0 + (size_t)64 * K;
    const unsigned short* gW0 = W + (size_t)(n0 + srow) * K + skk;
    const unsigned short* gW1 = gW0 + (size_t)64 * K;
    char* lA0 = (char*)As + wv * 1024;
    char* lA1 = lA0 + 4096;
    char* lW0 = (char*)Ws + wv * 1024;
    char* lW1 = lW0 + 4096;

    for (int k0 = 0; k0 < K; k0 += 32) {
        __syncthreads();                 // prior iter's ds_reads done
        load_lds16(gA0 + k0, lA0);
        load_lds16(gA1 + k0, lA1);
        load_lds16(gW0 + k0, lW0);
        load_lds16(gW1 + k0, lW1);
        __syncthreads();                 // drains vmcnt -> LDS visible

        short8 af[4], wf[4];
#pragma unroll
        for (int i = 0; i < 4; i++)
            af[i] = *(const short8*)&As[(wr + i * 16 + l15) * 32 + quad * 8];
#pragma unroll
        for (int j = 0; j < 4; j++)
            wf[j] = *(const short8*)&Ws[(wc + j * 16 + l15) * 32 + quad * 8];
#pragma unroll
        for (int i = 0; i < 4; i++)
#pragma unroll
            for (int j = 0; j < 4; j++)
                acc[i][j] = __builtin_amdgcn_mfma_f32_16x16x32_bf16(
                    af[i], wf[j], acc[i][j], 0, 0, 0);
    }

#pragma unroll
    for (int i = 0; i < 4; i++) {
        const int gr = m0 + wr + i * 16 + quad * 4;
#pragma unroll
        for (int j = 0; j < 4; j++) {
            const int gc = n0 + wc + j * 16 + l15;
            const float bv = bias[gc];
#pragma unroll
            for (int r = 0; r < 4; r++) {
                float v = acc[i][j][r] + bv;
                if (GELU) v = gelu_fast(v);
                if (RES)  v += res[(size_t)(gr + r) * N + gc];
                if (WF32) outF[(size_t)(gr + r) * N + gc] = v;
                if (WB16) outB[(size_t)(gr + r) * N + gc] = f2b(v);
            }
        }
    }
}

// ---------------------------------------------------------------------------
// Patch-embed MFMA GEMM: A gathered from bf16 image xb, W = conv_w bf16.
// ---------------------------------------------------------------------------
__global__ __launch_bounds__(256) void patch_mfma_kernel(
    const unsigned short* __restrict__ xb, const unsigned short* __restrict__ W,
    const float* __restrict__ bias, float* __restrict__ outF)
{
    __shared__ unsigned short As[128 * 32];
    __shared__ unsigned short Ws[128 * 32];

    const int t    = threadIdx.x;
    const int m0   = blockIdx.x * 128;
    const int n0   = blockIdx.y * 128;
    const int wv   = t >> 6, lane = t & 63;
    const int wr   = (wv >> 1) * 64, wc = (wv & 1) * 64;
    const int l15  = lane & 15, quad = lane >> 4;

    f32x4 acc[4][4];
#pragma unroll
    for (int i = 0; i < 4; i++)
#pragma unroll
        for (int j = 0; j < 4; j++)
#pragma unroll
            for (int r = 0; r < 4; r++) acc[i][j][r] = 0.0f;

    const int srow = wv * 16 + (lane >> 2);
    const int skk  = (lane & 3) * 8;   // k-offset within BK: 0,8,16,24
    size_t xoff[2];
#pragma unroll
    for (int s = 0; s < 2; s++) {
        const int m  = m0 + s * 64 + srow;
        const int b  = m >> 10;
        const int idx = m & 1023;
        const int hh = idx >> 5, ww = idx & 31;
        xoff[s] = ((size_t)(b * 3) * 512 + (size_t)(hh * 16)) * 512 + ww * 16;
    }
    const unsigned short* gW0 = W + (size_t)(n0 + srow) * 768 + skk;
    const unsigned short* gW1 = gW0 + (size_t)64 * 768;
    char* lA0 = (char*)As + wv * 1024;
    char* lA1 = lA0 + 4096;
    char* lW0 = (char*)Ws + wv * 1024;
    char* lW1 = lW0 + 4096;

    for (int k0 = 0; k0 < 768; k0 += 32) {
        const int k  = k0 + skk;
        const int c  = k >> 8;
        const int ph = (k >> 4) & 15;
        const int pw = k & 15;          // 0 or 8
        const size_t koff = (size_t)c * 262144 + (size_t)ph * 512 + pw;
        __syncthreads();
        load_lds16(xb + xoff[0] + koff, lA0);
        load_lds16(xb + xoff[1] + koff, lA1);
        load_lds16(gW0 + k0, lW0);
        load_lds16(gW1 + k0, lW1);
        __syncthreads();

        short8 af[4], wf[4];
#pragma unroll
        for (int i = 0; i < 4; i++)
            af[i] = *(const short8*)&As[(wr + i * 16 + l15) * 32 + quad * 8];
#pragma unroll
        for (int j = 0; j < 4; j++)
            wf[j] = *(const short8*)&Ws[(wc + j * 16 + l15) * 32 + quad * 8];
#pragma unroll
        for (int i = 0; i < 4; i++)
#pragma unroll
            for (int j = 0; j < 4; j++)
                acc[i][j] = __builtin_amdgcn_mfma_f32_16x16x32_bf16(
                    af[i], wf[j], acc[i][j], 0, 0, 0);
    }

#pragma unroll
    for (int i = 0; i < 4; i++) {
        const int gr = m0 + wr + i * 16 + quad * 4;
#pragma unroll
        for (int j = 0; j < 4; j++) {
            const int gc = n0 + wc + j * 16 + l15;
            const float bv = bias[gc];
#pragma unroll
            for (int r = 0; r < 4; r++)
                outF[(size_t)(gr + r) * 256 + gc] = acc[i][j][r] + bv;
        }
    }
}

// ---------------------------------------------------------------------------
// LayerNorm + PE (table lookup). One block = one token (256 features).
// ---------------------------------------------------------------------------
__global__ __launch_bounds__(256) void ln_pe_kernel(
    const float* __restrict__ in, const float* __restrict__ w,
    const float* __restrict__ b, const float* __restrict__ pe_t,
    float* __restrict__ outF, unsigned short* __restrict__ outB)
{
    const int m = blockIdx.x;
    const int d = threadIdx.x;
    float v = in[(size_t)m * 256 + d];

    float s = v, s2 = v * v;
#pragma unroll
    for (int off = 32; off > 0; off >>= 1) {
        s  += __shfl_down(s,  off, 64);
        s2 += __shfl_down(s2, off, 64);
    }
    __shared__ float ss[4], ss2[4], stats[2];
    const int lane = d & 63, wid = d >> 6;
    if (lane == 0) { ss[wid] = s; ss2[wid] = s2; }
    __syncthreads();
    if (d == 0) {
        float a  = ss[0] + ss[1] + ss[2] + ss[3];
        float a2 = ss2[0] + ss2[1] + ss2[2] + ss2[3];
        float mean = a * (1.0f / 256.0f);
        float var  = a2 * (1.0f / 256.0f) - mean * mean;
        stats[0] = mean;
        stats[1] = rsqrtf(var + 1e-5f);
    }
    __syncthreads();
    const float mean = stats[0], rstd = stats[1];

    const int pos = m & 1023;
    float pe = pe_t[pos * 256 + d];

    float o = (v - mean) * rstd * w[d] + b[d] + pe;
    outF[(size_t)m * 256 + d] = o;
    outB[(size_t)m * 256 + d] = f2b(o);
}

// ---------------------------------------------------------------------------
// MFMA windowed attention. One block = one (batch, window, head).
// ---------------------------------------------------------------------------
__global__ __launch_bounds__(256) void attn_mfma_kernel(
    const unsigned short* __restrict__ qkv, unsigned short* __restrict__ out)
{
    __shared__ unsigned short Ps[64 * 72];   // P, stride 72 (b128-aligned, padded)
    __shared__ unsigned short Vt[32 * 72];   // V^T [headdim][key]

    const int blk = blockIdx.x;        // 0..4095
    const int h = blk & 7;
    const int w = (blk >> 3) & 15;
    const int b = blk >> 7;
    const int m_base = b * 1024 + w * 64;

    const int t = threadIdx.x;
    const int wv = t >> 6, lane = t & 63;
    const int l15 = lane & 15, quad = lane >> 4;

    // ---- stage V^T (cooperative, 8 elems/thread) ----
    {
        const int row = t >> 2;             // key 0..63
        const int c0  = (t & 3) * 8;        // headdim chunk
        const unsigned short* src = qkv + (size_t)(m_base + row) * 768 + 512 + h * 32 + c0;
        us8v v = *(const us8v*)src;
#pragma unroll
        for (int j = 0; j < 8; j++) Vt[(c0 + j) * 72 + row] = v[j];
    }

    // ---- QK^T: S strip (16x64) = 4 MFMAs ----
    short8 aq = *(const short8*)(qkv + (size_t)(m_base + wv * 16 + l15) * 768 + h * 32 + quad * 8);
    f32x4 c[4];
#pragma unroll
    for (int j = 0; j < 4; j++) {
        short8 bk = *(const short8*)(qkv + (size_t)(m_base + j * 16 + l15) * 768 + 256 + h * 32 + quad * 8);
        f32x4 z = {0.0f, 0.0f, 0.0f, 0.0f};
        c[j] = __builtin_amdgcn_mfma_f32_16x16x32_bf16(aq, bk, z, 0, 0, 0);
    }

    // ---- softmax over keys (row = quad*4+reg, col = j*16+l15) ----
    const float scale = 0.17677669529663687f; // 1/sqrt(32)
    float sm[4];
#pragma unroll
    for (int r = 0; r < 4; r++) {
        float m0 = -1e30f;
#pragma unroll
        for (int j = 0; j < 4; j++) { c[j][r] *= scale; m0 = fmaxf(m0, c[j][r]); }
#pragma unroll
        for (int d = 1; d < 16; d <<= 1) m0 = fmaxf(m0, __shfl_xor(m0, d, 64));
        float s0 = 0.0f;
#pragma unroll
        for (int j = 0; j < 4; j++) { float e = __expf(c[j][r] - m0); c[j][r] = e; s0 += e; }
#pragma unroll
        for (int d = 1; d < 16; d <<= 1) s0 += __shfl_xor(s0, d, 64);
        sm[r] = __builtin_amdgcn_rcpf(s0);
    }

    // ---- write P (bf16) to LDS ----
#pragma unroll
    for (int r = 0; r < 4; r++) {
        const int prow = wv * 16 + quad * 4 + r;
#pragma unroll
        for (int j = 0; j < 4; j++)
            Ps[prow * 72 + j * 16 + l15] = f2b(c[j][r] * sm[r]);
    }
    __syncthreads();

    // ---- PV: O strip (16x32) = 4 MFMAs ----
    short8 ap0 = *(const short8*)&Ps[(wv * 16 + l15) * 72 + quad * 8];
    short8 ap1 = *(const short8*)&Ps[(wv * 16 + l15) * 72 + 32 + quad * 8];
    f32x4 o[2];
#pragma unroll
    for (int nt = 0; nt < 2; nt++) {
        short8 bv0 = *(const short8*)&Vt[(nt * 16 + l15) * 72 + quad * 8];
        short8 bv1 = *(const short8*)&Vt[(nt * 16 + l15) * 72 + 32 + quad * 8];
        f32x4 z = {0.0f, 0.0f, 0.0f, 0.0f};
        o[nt] = __builtin_amdgcn_mfma_f32_16x16x32_bf16(ap0, bv0, z, 0, 0, 0);
        o[nt] = __builtin_amdgcn_mfma_f32_16x16x32_bf16(ap1, bv1, o[nt], 0, 0, 0);
    }

    // ---- write O (bf16) ----
#pragma unroll
    for (int nt = 0; nt < 2; nt++) {
#pragma unroll
        for (int r = 0; r < 4; r++) {
            const int row = m_base + wv * 16 + quad * 4 + r;
            out[(size_t)row * 256 + h * 32 + nt * 16 + l15] = f2b(o[nt][r]);
        }
    }
}

// ---------------------------------------------------------------------------
// Workspace layout (bytes), total ~186.5 MB (same footprint as round 3).
// PE table parked at ws+100663296 (inside SLOT_B tail: used only between
// pe_init and ln_pe; later clobbered by qkvb — safe by ordering).
// ---------------------------------------------------------------------------
extern "C" void kernel_launch(void* const* d_in, const int* in_sizes, int n_in,
                              void* d_out, int out_size, void* d_ws, size_t ws_size,
                              hipStream_t stream)
{
    const float* x      = (const float*)d_in[0];
    const float* conv_w = (const float*)d_in[1];
    const float* conv_b = (const float*)d_in[2];
    const float* ln_w   = (const float*)d_in[3];
    const float* ln_b   = (const float*)d_in[4];
    const float* qkv_w  = (const float*)d_in[5];
    const float* qkv_b  = (const float*)d_in[6];
    const float* proj_w = (const float*)d_in[7];
    const float* proj_b = (const float*)d_in[8];
    const float* ff_w1  = (const float*)d_in[9];
    const float* ff_b1  = (const float*)d_in[10];
    const float* ff_w2  = (const float*)d_in[11];
    const float* ff_b2  = (const float*)d_in[12];
    float* out = (float*)d_out;

    char* ws = (char*)d_ws;
    unsigned short* xb    = (unsigned short*)(ws);                 // SLOT_A
    unsigned short* hidb  = (unsigned short*)(ws);                 // SLOT_A reuse
    float*          h0    = (float*)(ws + 67108864);               // SLOT_B
    unsigned short* qkvb  = (unsigned short*)(ws + 67108864);      // SLOT_B reuse
    float*          pe_t  = (float*)(ws + 100663296);              // SLOT_B tail
    float*          h1f   = (float*)(ws + 117440512);
    unsigned short* h1b   = (unsigned short*)(ws + 150994944);     // SLOT_C
    unsigned short* aob   = (unsigned short*)(ws + 150994944);     // SLOT_C reuse
    unsigned short* f1b   = (unsigned short*)(ws + 167772160);     // SLOT_D
    unsigned short* h2b   = (unsigned short*)(ws + 167772160);     // SLOT_D reuse
    unsigned short* wbase = (unsigned short*)(ws + 184549376);
    unsigned short* conv_wb = wbase;                 // 196608
    unsigned short* qkv_wb  = wbase + 196608;        // 196608
    unsigned short* proj_wb = wbase + 393216;        // 65536
    unsigned short* ff_w1b  = wbase + 458752;        // 262144
    unsigned short* ff_w2b  = wbase + 720896;        // 262144

    const int M = M_TOK;
    dim3 blk(256);

    // K0: conversions + PE table
    cvt_f2b_kernel<<<dim3(25165824 / 1024), blk, 0, stream>>>(x, xb, 25165824);
    cvt_f2b_kernel<<<dim3(196608 / 1024), blk, 0, stream>>>(conv_w, conv_wb, 196608);
    cvt_f2b_kernel<<<dim3(196608 / 1024), blk, 0, stream>>>(qkv_w, qkv_wb, 196608);
    cvt_f2b_kernel<<<dim3(65536 / 1024), blk, 0, stream>>>(proj_w, proj_wb, 65536);
    cvt_f2b_kernel<<<dim3(262144 / 1024), blk, 0, stream>>>(ff_w1, ff_w1b, 262144);
    cvt_f2b_kernel<<<dim3(262144 / 1024), blk, 0, stream>>>(ff_w2, ff_w2b, 262144);
    pe_init_kernel<<<dim3(1024), blk, 0, stream>>>(pe_t);

    // K1: patch embed -> h0 (fp32)
    patch_mfma_kernel<<<dim3(M / 128, 2), blk, 0, stream>>>(xb, conv_wb, conv_b, h0);
    // K2: LN + PE -> h1f (fp32 residual) + h1b (bf16)
    ln_pe_kernel<<<dim3(M), blk, 0, stream>>>(h0, ln_w, ln_b, pe_t, h1f, h1b);
    // K3: FFN1a: gelu(h1 @ w1^T + b1) -> hidb (bf16)
    mfma_gemm_kernel<true, false, false, true><<<dim3(M / 128, 8), blk, 0, stream>>>(
        h1b, ff_w1b, ff_b1, nullptr, nullptr, hidb, M, 1024, 256);
    // K4: FFN1b: hidb @ w2^T + b2 -> f1b (bf16)
    mfma_gemm_kernel<false, false, false, true><<<dim3(M / 128, 2), blk, 0, stream>>>(
        hidb, ff_w2b, ff_b2, nullptr, nullptr, f1b, M, 256, 1024);
    // K5: qkv: f1b @ qkv_w^T + qkv_b -> qkvb (bf16)
    mfma_gemm_kernel<false, false, false, true><<<dim3(M / 128, 6), blk, 0, stream>>>(
        f1b, qkv_wb, qkv_b, nullptr, nullptr, qkvb, M, 768, 256);
    // K6: windowed attention (MFMA): qkvb -> aob (bf16)
    attn_mfma_kernel<<<dim3(4096), blk, 0, stream>>>(qkvb, aob);
    // K7: proj + residual(h1f): aob @ proj_w^T + proj_b + h1f -> out + h2b
    mfma_gemm_kernel<false, true, true, true><<<dim3(M / 128, 2), blk, 0, stream>>>(
        aob, proj_wb, proj_b, h1f, out, h2b, M, 256, 256);
    // K8: FFN2a: gelu(h2b @ w1^T + b1) -> hidb (bf16)
    mfma_gemm_kernel<true, false, false, true><<<dim3(M / 128, 8), blk, 0, stream>>>(
        h2b, ff_w1b, ff_b1, nullptr, nullptr, hidb, M, 1024, 256);
    // K9: FFN2b + final residual: hidb @ w2^T + b2 + out -> out
    mfma_gemm_kernel<false, true, true, false><<<dim3(M / 128, 2), blk, 0, stream>>>(
        hidb, ff_w2b, ff_b2, out, out, nullptr, M, 256, 1024);
}